// Round 1
// baseline (528.065 us; speedup 1.0000x reference)
//
#include <hip/hip_runtime.h>
#include <hip/hip_bf16.h>
#include <stdint.h>

#define TT 512
#define NB 128
#define EM 256
#define UN 256

typedef short bf16x8 __attribute__((ext_vector_type(8)));
typedef float floatx4 __attribute__((ext_vector_type(4)));
typedef _Float16 h2 __attribute__((ext_vector_type(2)));

__device__ inline unsigned short f2bf(float f) {
    union { float f; uint32_t u; } v; v.f = f;
    uint32_t r = v.u + 0x7fffu + ((v.u >> 16) & 1u);
    return (unsigned short)(r >> 16);
}
__device__ inline float bf2f(unsigned short b) {
    union { uint32_t u; float f; } v; v.u = ((uint32_t)b) << 16;
    return v.f;
}

__device__ inline float dot2f(h2 a, h2 b, float c) {
#if defined(__has_builtin)
#if __has_builtin(__builtin_amdgcn_fdot2)
    return __builtin_amdgcn_fdot2(a, b, c, false);
#else
    return c + (float)a[0]*(float)b[0] + (float)a[1]*(float)b[1];
#endif
#else
    return c + (float)a[0]*(float)b[0] + (float)a[1]*(float)b[1];
#endif
}

// ---------------------------------------------------------------------------
// Kernel 1: repack W (f32 [256 u][256 e]) into MFMA B-fragment order, bf16.
// wfrag[(kt*16+nt)*64 + lane][j] = W[nt*16 + (lane&15)][kt*32 + (lane>>4)*8 + j]
// so each wave's b-frag load is one coalesced dwordx4.
// ---------------------------------------------------------------------------
__global__ void k_wfrag(const float* __restrict__ W, unsigned short* __restrict__ wfrag) {
    int idx = blockIdx.x * blockDim.x + threadIdx.x;  // 0..8191
    int lane = idx & 63;
    int tile = idx >> 6;            // kt*16 + nt
    int nt = tile & 15, kt = tile >> 4;
    int u  = nt * 16 + (lane & 15);
    int e0 = kt * 32 + (lane >> 4) * 8;
    unsigned short* dst = wfrag + (size_t)idx * 8;
    #pragma unroll
    for (int j = 0; j < 8; j++) dst[j] = f2bf(W[u * EM + e0 + j]);
}

// ---------------------------------------------------------------------------
// Kernel 2: xw[b][t][u] = sum_e emb[sent[b][t]][e] * W[u][e], bf16 out.
// Grid: 1024 blocks x 256 thr. Each wave: 16 rows x 256 cols via 16x16x32 MFMA.
// A-frags gathered straight from emb_table (no LDS), B-frags from wfrag (L2-hot).
// ---------------------------------------------------------------------------
__global__ __launch_bounds__(256, 2) void k_gemm(
    const int* __restrict__ sent, const float* __restrict__ emb,
    const unsigned short* __restrict__ wfrag, unsigned short* __restrict__ xw)
{
    int w    = threadIdx.x >> 6;
    int lane = threadIdx.x & 63;
    int m  = lane & 15;
    int kg = lane >> 4;
    int row = blockIdx.x * 64 + w * 16 + m;
    int tok = sent[row];
    const float* arow = emb + (size_t)tok * EM;

    bf16x8 a[8];
    #pragma unroll
    for (int kt = 0; kt < 8; kt++) {
        const float* p = arow + kt * 32 + kg * 8;
        float4 f0 = *(const float4*)p;
        float4 f1 = *(const float4*)(p + 4);
        bf16x8 t;
        t[0] = (short)f2bf(f0.x); t[1] = (short)f2bf(f0.y);
        t[2] = (short)f2bf(f0.z); t[3] = (short)f2bf(f0.w);
        t[4] = (short)f2bf(f1.x); t[5] = (short)f2bf(f1.y);
        t[6] = (short)f2bf(f1.z); t[7] = (short)f2bf(f1.w);
        a[kt] = t;
    }

    floatx4 acc[16];
    #pragma unroll
    for (int nt = 0; nt < 16; nt++) acc[nt] = floatx4{0.f, 0.f, 0.f, 0.f};

    #pragma unroll
    for (int kt = 0; kt < 8; kt++) {
        #pragma unroll
        for (int nt = 0; nt < 16; nt++) {
            bf16x8 bfr = *(const bf16x8*)(wfrag + ((size_t)(kt * 16 + nt) * 64 + lane) * 8);
            acc[nt] = __builtin_amdgcn_mfma_f32_16x16x32_bf16(a[kt], bfr, acc[nt], 0, 0, 0);
        }
    }

    // D layout: row = (lane>>4)*4 + r, col = lane&15 (m89-verified)
    int rbase = blockIdx.x * 64 + w * 16 + (lane >> 4) * 4;
    int cbase = lane & 15;
    #pragma unroll
    for (int nt = 0; nt < 16; nt++) {
        #pragma unroll
        for (int r = 0; r < 4; r++) {
            xw[(size_t)(rbase + r) * UN + nt * 16 + cbase] = f2bf(acc[nt][r]);
        }
    }
}

// ---------------------------------------------------------------------------
// Kernel 3: per-batch RNN scan + MLP head + softmax.
// Grid: 128 blocks (one per batch row) x 1024 threads.
// Thread t = 4u + j holds U[u][64j..64j+64) as 32 packed f16 pairs in VGPRs.
// h double-buffered in LDS (f16), one barrier per step.
// ---------------------------------------------------------------------------
__global__ __launch_bounds__(1024, 4) void k_rnn(
    const float* __restrict__ Umat, const unsigned short* __restrict__ xw,
    const float* __restrict__ W1, const float* __restrict__ b1,
    const float* __restrict__ W2, const float* __restrict__ b2,
    float* __restrict__ out)
{
    __shared__ __align__(16) _Float16 hb[2][256];
    __shared__ float hid[32];
    const int t = threadIdx.x;
    const int u = t >> 2;
    const int j = t & 3;
    const int b = blockIdx.x;

    // U chunk -> registers (f16 pairs). One-time 256 B/thread from L2/L3.
    h2 ureg[32];
    const float* ubase = Umat + u * UN + j * 64;
    #pragma unroll
    for (int i = 0; i < 16; i++) {
        float4 f = *(const float4*)(ubase + i * 4);
        h2 p0; p0[0] = (_Float16)f.x; p0[1] = (_Float16)f.y;
        h2 p1; p1[0] = (_Float16)f.z; p1[1] = (_Float16)f.w;
        ureg[2 * i]     = p0;
        ureg[2 * i + 1] = p1;
    }

    if (t < 256) hb[0][t] = (_Float16)0.f;
    __syncthreads();

    const unsigned short* xwb = xw + (size_t)b * TT * UN + u;
    float xv = bf2f(xwb[0]);
    int cur = 0;

    for (int s = 0; s < TT; s++) {
        // prefetch next timestep's xw (L2-resident, broadcast over 4 j-lanes)
        float xn = bf2f(xwb[(size_t)(s + 1 < TT ? s + 1 : s) * UN]);

        const h2* hp = (const h2*)&hb[cur][j * 64];
        float a0 = 0.f, a1 = 0.f, a2 = 0.f, a3 = 0.f;
        #pragma unroll
        for (int i = 0; i < 8; i++) {
            a0 = dot2f(ureg[i],      hp[i],      a0);
            a1 = dot2f(ureg[i + 8],  hp[i + 8],  a1);
            a2 = dot2f(ureg[i + 16], hp[i + 16], a2);
            a3 = dot2f(ureg[i + 24], hp[i + 24], a3);
        }
        float acc = (a0 + a1) + (a2 + a3);
        acc += __shfl_xor(acc, 1);
        acc += __shfl_xor(acc, 2);

        float z  = xv + acc;
        float e  = __expf(2.f * z);
        float hn = 1.f - 2.f * __builtin_amdgcn_rcpf(e + 1.f);   // tanh(z)

        if (j == 0) hb[cur ^ 1][u] = (_Float16)hn;
        __syncthreads();
        cur ^= 1;
        xv = xn;
    }

    // ---- head: hidden = relu(h @ W1 + b1); logits = hidden @ W2 + b2; softmax
    if (t < 32) {
        float a = b1[t];
        for (int k = 0; k < 256; k++) a += (float)hb[cur][k] * W1[k * 32 + t];
        hid[t] = fmaxf(a, 0.f);
    }
    __syncthreads();
    if (t == 0) {
        float l0 = b2[0], l1 = b2[1];
        #pragma unroll
        for (int i = 0; i < 32; i++) {
            float hv = hid[i];
            l0 += hv * W2[2 * i];
            l1 += hv * W2[2 * i + 1];
        }
        float mx = fmaxf(l0, l1);
        float e0 = __expf(l0 - mx), e1 = __expf(l1 - mx);
        float inv = 1.f / (e0 + e1);
        out[2 * b]     = e0 * inv;
        out[2 * b + 1] = e1 * inv;
    }
}

extern "C" void kernel_launch(void* const* d_in, const int* in_sizes, int n_in,
                              void* d_out, int out_size, void* d_ws, size_t ws_size,
                              hipStream_t stream) {
    const int*   sent = (const int*)d_in[0];
    const float* emb  = (const float*)d_in[1];
    const float* W    = (const float*)d_in[2];
    const float* U    = (const float*)d_in[3];
    const float* W1   = (const float*)d_in[4];
    const float* b1   = (const float*)d_in[5];
    const float* W2   = (const float*)d_in[6];
    const float* b2   = (const float*)d_in[7];
    float* out = (float*)d_out;

    unsigned short* xw    = (unsigned short*)d_ws;                          // 32 MB bf16 [B][T][U]
    unsigned short* wfrag = (unsigned short*)((char*)d_ws + (size_t)NB * TT * UN * 2);  // 128 KB

    k_wfrag<<<32, 256, 0, stream>>>(W, wfrag);
    k_gemm<<<(NB * TT) / 64, 256, 0, stream>>>(sent, emb, wfrag, xw);
    k_rnn<<<NB, 1024, 0, stream>>>(U, xw, W1, b1, W2, b2, out);
}

// Round 2
// 448.172 us; speedup vs baseline: 1.1783x; 1.1783x over previous
//
#include <hip/hip_runtime.h>
#include <hip/hip_bf16.h>
#include <stdint.h>

#define TT 512
#define NB 128
#define EM 256
#define UN 256

typedef short bf16x8 __attribute__((ext_vector_type(8)));
typedef float floatx4 __attribute__((ext_vector_type(4)));
typedef _Float16 h2 __attribute__((ext_vector_type(2)));
typedef _Float16 h4 __attribute__((ext_vector_type(4)));

__device__ inline unsigned short f2bf(float f) {
    union { float f; uint32_t u; } v; v.f = f;
    uint32_t r = v.u + 0x7fffu + ((v.u >> 16) & 1u);
    return (unsigned short)(r >> 16);
}
__device__ inline float bf2f(unsigned short b) {
    union { uint32_t u; float f; } v; v.u = ((uint32_t)b) << 16;
    return v.f;
}

__device__ inline float dot2f(h2 a, h2 b, float c) {
#if defined(__has_builtin)
#if __has_builtin(__builtin_amdgcn_fdot2)
    return __builtin_amdgcn_fdot2(a, b, c, false);
#else
    return c + (float)a[0]*(float)b[0] + (float)a[1]*(float)b[1];
#endif
#else
    return c + (float)a[0]*(float)b[0] + (float)a[1]*(float)b[1];
#endif
}

// ---------------------------------------------------------------------------
// Kernel 1: repack W (f32 [256 u][256 e]) into MFMA B-fragment order, bf16.
// ---------------------------------------------------------------------------
__global__ void k_wfrag(const float* __restrict__ W, unsigned short* __restrict__ wfrag) {
    int idx = blockIdx.x * blockDim.x + threadIdx.x;  // 0..8191
    int lane = idx & 63;
    int tile = idx >> 6;            // kt*16 + nt
    int nt = tile & 15, kt = tile >> 4;
    int u  = nt * 16 + (lane & 15);
    int e0 = kt * 32 + (lane >> 4) * 8;
    unsigned short* dst = wfrag + (size_t)idx * 8;
    #pragma unroll
    for (int j = 0; j < 8; j++) dst[j] = f2bf(W[u * EM + e0 + j]);
}

// ---------------------------------------------------------------------------
// Kernel 2: xw[b][t][u] = sum_e emb[sent[b][t]][e] * W[u][e], bf16 out.
// (unchanged from passing R0 version)
// ---------------------------------------------------------------------------
__global__ __launch_bounds__(256, 2) void k_gemm(
    const int* __restrict__ sent, const float* __restrict__ emb,
    const unsigned short* __restrict__ wfrag, unsigned short* __restrict__ xw)
{
    int w    = threadIdx.x >> 6;
    int lane = threadIdx.x & 63;
    int m  = lane & 15;
    int kg = lane >> 4;
    int row = blockIdx.x * 64 + w * 16 + m;
    int tok = sent[row];
    const float* arow = emb + (size_t)tok * EM;

    bf16x8 a[8];
    #pragma unroll
    for (int kt = 0; kt < 8; kt++) {
        const float* p = arow + kt * 32 + kg * 8;
        float4 f0 = *(const float4*)p;
        float4 f1 = *(const float4*)(p + 4);
        bf16x8 t;
        t[0] = (short)f2bf(f0.x); t[1] = (short)f2bf(f0.y);
        t[2] = (short)f2bf(f0.z); t[3] = (short)f2bf(f0.w);
        t[4] = (short)f2bf(f1.x); t[5] = (short)f2bf(f1.y);
        t[6] = (short)f2bf(f1.z); t[7] = (short)f2bf(f1.w);
        a[kt] = t;
    }

    floatx4 acc[16];
    #pragma unroll
    for (int nt = 0; nt < 16; nt++) acc[nt] = floatx4{0.f, 0.f, 0.f, 0.f};

    #pragma unroll
    for (int kt = 0; kt < 8; kt++) {
        #pragma unroll
        for (int nt = 0; nt < 16; nt++) {
            bf16x8 bfr = *(const bf16x8*)(wfrag + ((size_t)(kt * 16 + nt) * 64 + lane) * 8);
            acc[nt] = __builtin_amdgcn_mfma_f32_16x16x32_bf16(a[kt], bfr, acc[nt], 0, 0, 0);
        }
    }

    int rbase = blockIdx.x * 64 + w * 16 + (lane >> 4) * 4;
    int cbase = lane & 15;
    #pragma unroll
    for (int nt = 0; nt < 16; nt++) {
        #pragma unroll
        for (int r = 0; r < 4; r++) {
            xw[(size_t)(rbase + r) * UN + nt * 16 + cbase] = f2bf(acc[nt][r]);
        }
    }
}

// ---------------------------------------------------------------------------
// Kernel 3 (v2): per-batch RNN scan, 256 threads/block.
// Thread t: j = t&3 (k-slice of 64 h-values), g = t>>2 (units 4g..4g+3).
// U held in regs (128 h2/thread). h in LDS: 2 buffers x 4 slices x 144 B
// (128 B data + 16 B pad -> conflict-free b128 reads).
// Per step: 8 ds_read_b128 (conflict-free) + 128 dot2 + 2 shfl_xor reduce +
// poly tanh + 1 b64 LDS write (j==0 lanes) + 1 barrier.
// ---------------------------------------------------------------------------
__global__ __launch_bounds__(256, 1) void k_rnn(
    const float* __restrict__ Umat, const unsigned short* __restrict__ xw,
    const float* __restrict__ W1, const float* __restrict__ b1,
    const float* __restrict__ W2, const float* __restrict__ b2,
    float* __restrict__ out)
{
    __shared__ __align__(16) unsigned char hbuf[2 * 576];   // 2 x (4 slices x 144 B)
    __shared__ float hid[32];
    const int t = threadIdx.x;
    const int j = t & 3;
    const int g = t >> 2;            // units 4g .. 4g+3
    const int b = blockIdx.x;

    // U -> registers: ureg[n][i] = U[4g+n][j*64 + 2i .. 2i+1] as f16 pair
    h2 ureg[4][32];
    #pragma unroll
    for (int n = 0; n < 4; n++) {
        const float* up = Umat + (size_t)(4 * g + n) * UN + j * 64;
        #pragma unroll
        for (int i = 0; i < 16; i++) {
            float4 f = *(const float4*)(up + 4 * i);
            h2 p0; p0[0] = (_Float16)f.x; p0[1] = (_Float16)f.y;
            h2 p1; p1[0] = (_Float16)f.z; p1[1] = (_Float16)f.w;
            ureg[n][2 * i]     = p0;
            ureg[n][2 * i + 1] = p1;
        }
    }

    // zero both h buffers (1152 B = 288 dwords)
    for (int idx = t; idx < 288; idx += 256) ((uint32_t*)hbuf)[idx] = 0u;
    __syncthreads();

    const unsigned short* xwp = xw + (size_t)b * TT * UN + 4 * g;
    ushort4 xv = *(const ushort4*)xwp;
    int cur = 0;
    const int wslice = g >> 4;          // (4g)>>6
    const int wpos8  = (g & 15) * 8;    // byte offset within slice: (4g&63)*2

    const float c3 = -0.33333334f, c5 = 0.13333334f, c7 = -0.05396825f, c9 = 0.02186949f;

    for (int s = 0; s < TT; s++) {
        int sn = (s + 1 < TT) ? s + 1 : s;
        ushort4 xn = *(const ushort4*)(xwp + (size_t)sn * UN);

        // h slice -> regs: 8 conflict-free ds_read_b128
        h2 hreg[32];
        const uint4* hp = (const uint4*)(hbuf + cur * 576 + j * 144);
        #pragma unroll
        for (int i = 0; i < 8; i++) ((uint4*)hreg)[i] = hp[i];

        float a0[4] = {0.f, 0.f, 0.f, 0.f};
        float a1[4] = {0.f, 0.f, 0.f, 0.f};
        #pragma unroll
        for (int i = 0; i < 16; i++) {
            #pragma unroll
            for (int n = 0; n < 4; n++) {
                a0[n] = dot2f(ureg[n][i],      hreg[i],      a0[n]);
                a1[n] = dot2f(ureg[n][i + 16], hreg[i + 16], a1[n]);
            }
        }

        float z[4];
        {
            unsigned short xs[4] = {xv.x, xv.y, xv.z, xv.w};
            #pragma unroll
            for (int n = 0; n < 4; n++) {
                float acc = a0[n] + a1[n];
                acc += __shfl_xor(acc, 1);
                acc += __shfl_xor(acc, 2);
                z[n] = bf2f(xs[n]) + acc;
            }
        }

        float hn[4];
        float mx = fmaxf(fmaxf(fabsf(z[0]), fabsf(z[1])), fmaxf(fabsf(z[2]), fabsf(z[3])));
        if (__builtin_expect(mx > 0.75f, 0)) {
            #pragma unroll
            for (int n = 0; n < 4; n++) {
                float e = __expf(2.f * z[n]);
                hn[n] = 1.f - 2.f * __builtin_amdgcn_rcpf(e + 1.f);
            }
        } else {
            #pragma unroll
            for (int n = 0; n < 4; n++) {
                float x2 = z[n] * z[n];
                float p = fmaf(x2, c9, c7);
                p = fmaf(x2, p, c5);
                p = fmaf(x2, p, c3);
                hn[n] = fmaf(z[n] * x2, p, z[n]);
            }
        }

        if (j == 0) {
            h4 q;
            q[0] = (_Float16)hn[0]; q[1] = (_Float16)hn[1];
            q[2] = (_Float16)hn[2]; q[3] = (_Float16)hn[3];
            *(h4*)(hbuf + (cur ^ 1) * 576 + wslice * 144 + wpos8) = q;
        }
        __syncthreads();
        cur ^= 1;
        xv = xn;
    }

    // ---- head: hidden = relu(h @ W1 + b1); logits; softmax
    const unsigned char* hb = hbuf + cur * 576;
    if (t < 32) {
        float a = b1[t];
        for (int k = 0; k < 256; k++) {
            float hv = (float)(*(const _Float16*)(hb + (k >> 6) * 144 + (k & 63) * 2));
            a += hv * W1[k * 32 + t];
        }
        hid[t] = fmaxf(a, 0.f);
    }
    __syncthreads();
    if (t == 0) {
        float l0 = b2[0], l1 = b2[1];
        #pragma unroll
        for (int i = 0; i < 32; i++) {
            float hv = hid[i];
            l0 += hv * W2[2 * i];
            l1 += hv * W2[2 * i + 1];
        }
        float mx2 = fmaxf(l0, l1);
        float e0 = __expf(l0 - mx2), e1 = __expf(l1 - mx2);
        float inv = 1.f / (e0 + e1);
        out[2 * b]     = e0 * inv;
        out[2 * b + 1] = e1 * inv;
    }
}

extern "C" void kernel_launch(void* const* d_in, const int* in_sizes, int n_in,
                              void* d_out, int out_size, void* d_ws, size_t ws_size,
                              hipStream_t stream) {
    const int*   sent = (const int*)d_in[0];
    const float* emb  = (const float*)d_in[1];
    const float* W    = (const float*)d_in[2];
    const float* U    = (const float*)d_in[3];
    const float* W1   = (const float*)d_in[4];
    const float* b1   = (const float*)d_in[5];
    const float* W2   = (const float*)d_in[6];
    const float* b2   = (const float*)d_in[7];
    float* out = (float*)d_out;

    unsigned short* xw    = (unsigned short*)d_ws;                          // 32 MB bf16 [B][T][U]
    unsigned short* wfrag = (unsigned short*)((char*)d_ws + (size_t)NB * TT * UN * 2);  // 128 KB

    k_wfrag<<<32, 256, 0, stream>>>(W, wfrag);
    k_gemm<<<(NB * TT) / 64, 256, 0, stream>>>(sent, emb, wfrag, xw);
    k_rnn<<<NB, 256, 0, stream>>>(U, xw, W1, b1, W2, b2, out);
}